// Round 9
// baseline (3148.067 us; speedup 1.0000x reference)
//
#include <hip/hip_runtime.h>
#include <hip/hip_bf16.h>
#include <math.h>

// Sizes: V=50000, E=128, H=128, B=32, S=50, T=40, D=256, G=512 (4H), BS=1600
// M = BS*T = 64000 seq-steps for word layers.

__device__ __forceinline__ float sigm(float x) { return 1.f / (1.f + expf(-x)); }

// ---------------------------------------------------------------------------
// Generic 2D transpose: in[z][R][C] -> out[z][C][R]
// ---------------------------------------------------------------------------
__global__ void transpose_k(const float* __restrict__ in, float* __restrict__ out,
                            int R, int C) {
    __shared__ float tile[32][33];
    int z = blockIdx.z;
    in += (size_t)z * R * C;
    out += (size_t)z * R * C;
    int bx = blockIdx.x * 32, by = blockIdx.y * 32;
    int tx = threadIdx.x, ty = threadIdx.y; // 32 x 8
    #pragma unroll
    for (int j = 0; j < 32; j += 8) {
        tile[ty + j][tx] = in[(size_t)(by + ty + j) * C + bx + tx];
    }
    __syncthreads();
    #pragma unroll
    for (int j = 0; j < 32; j += 8) {
        out[(size_t)(bx + ty + j) * R + by + tx] = tile[tx][ty + j];
    }
}

// ---------------------------------------------------------------------------
// Pack word weights as float4 = [2 rows][2 gates]:
//   dst[((dir*ROWS2 + r2)*128 + k)*8 + gp*4 + f]
//   f: {row0 g0, row0 g1, row1 g0, row1 g1}, gates g = gp*2 + (f&1),
//   rows 0..E-1 from ih[dir][512][E], rows E.. from hh[dir][512][128].
// ---------------------------------------------------------------------------
__global__ void pack_w4(const float* __restrict__ ih, const float* __restrict__ hh,
                        float* __restrict__ dst, int E) {
    int ROWS2 = (E + 128) >> 1;
    size_t total = (size_t)2 * ROWS2 * 128 * 8;
    for (size_t i = (size_t)blockIdx.x * 256 + threadIdx.x; i < total;
         i += (size_t)gridDim.x * 256) {
        int f = (int)(i & 3);
        int gp = (int)((i >> 2) & 1);
        int k = (int)((i >> 3) & 127);
        size_t rr = i >> 10;
        int r2 = (int)(rr % ROWS2);
        int dir = (int)(rr / ROWS2);
        int row = r2 * 2 + (f >> 1);
        int gate = gp * 2 + (f & 1);
        float v = (row < E) ? ih[((size_t)dir * 512 + gate * 128 + k) * E + row]
                            : hh[((size_t)dir * 512 + gate * 128 + k) * 128 + (row - E)];
        dst[i] = v;
    }
}

// ---------------------------------------------------------------------------
// Pack W_ih for the x-part GEMM:  bt[e][c] with c = dir*512 + (gate*128+k),
// from ih[dir][512][E]. Also bias vector bv[c] from b[dir][512].
// ---------------------------------------------------------------------------
__global__ void pack_bt(const float* __restrict__ ih, const float* __restrict__ b,
                        float* __restrict__ bt, float* __restrict__ bv, int E) {
    size_t total = (size_t)E * 1024;
    for (size_t i = (size_t)blockIdx.x * 256 + threadIdx.x; i < total;
         i += (size_t)gridDim.x * 256) {
        int c = (int)(i & 1023);
        int e = (int)(i >> 10);
        int dir = c >> 9;
        int gk = c & 511;
        bt[i] = ih[((size_t)dir * 512 + gk) * E + e];
        if (e == 0) bv[c] = b[dir * 512 + gk];
    }
}

// ---------------------------------------------------------------------------
// x-part GEMM:  pre[n][c] = A[n][:K] @ bt[K][1024] + bv[c]
//   GATHER=1: A row n = emb[ids[n]] (K=128).  GATHER=0: A row n = A[n*K].
// 128x128 tiles, BK=32, 256 threads, 8x8 micro-tile. grid (Mc/128, 8).
// ---------------------------------------------------------------------------
template <int K, int GATHER>
__global__ __launch_bounds__(256, 4) void gemm_x(
    const float* __restrict__ A, const int* __restrict__ ids,
    const float* __restrict__ emb, const float* __restrict__ bt,
    const float* __restrict__ bv, float* __restrict__ C) {
    int n0 = blockIdx.x * 128;
    int c0 = blockIdx.y * 128;
    int tid = threadIdx.x;
    int tx = tid & 15, ty = tid >> 4;
    __shared__ float As[32][132]; // [kk][row]
    __shared__ float Bs[32][132]; // [kk][col]
    float acc[8][8];
    #pragma unroll
    for (int i = 0; i < 8; i++)
        #pragma unroll
        for (int j = 0; j < 8; j++) acc[i][j] = 0.f;

    for (int k0 = 0; k0 < K; k0 += 32) {
        #pragma unroll
        for (int it = 0; it < 4; it++) {
            int lin = tid + it * 256;
            int r = lin >> 3, kq = lin & 7;
            const float* src;
            if (GATHER) {
                src = emb + (size_t)ids[n0 + r] * 128;
            } else {
                src = A + (size_t)(n0 + r) * K;
            }
            float4 v = *(const float4*)&src[k0 + kq * 4];
            As[kq * 4 + 0][r] = v.x;
            As[kq * 4 + 1][r] = v.y;
            As[kq * 4 + 2][r] = v.z;
            As[kq * 4 + 3][r] = v.w;
        }
        #pragma unroll
        for (int it = 0; it < 4; it++) {
            int lin = tid + it * 256;
            int kk = lin >> 5, c4 = lin & 31;
            float4 v = *(const float4*)&bt[(size_t)(k0 + kk) * 1024 + c0 + c4 * 4];
            *(float4*)&Bs[kk][c4 * 4] = v;
        }
        __syncthreads();
        #pragma unroll 4
        for (int kk = 0; kk < 32; kk++) {
            float4 a0 = *(const float4*)&As[kk][ty * 8];
            float4 a1 = *(const float4*)&As[kk][ty * 8 + 4];
            float4 b0 = *(const float4*)&Bs[kk][tx * 8];
            float4 b1 = *(const float4*)&Bs[kk][tx * 8 + 4];
            const float av[8] = {a0.x, a0.y, a0.z, a0.w, a1.x, a1.y, a1.z, a1.w};
            const float bvv[8] = {b0.x, b0.y, b0.z, b0.w, b1.x, b1.y, b1.z, b1.w};
            #pragma unroll
            for (int i = 0; i < 8; i++)
                #pragma unroll
                for (int j = 0; j < 8; j++)
                    acc[i][j] = fmaf(av[i], bvv[j], acc[i][j]);
        }
        __syncthreads();
    }
    float bias8[8];
    #pragma unroll
    for (int j = 0; j < 8; j++) bias8[j] = bv[c0 + tx * 8 + j];
    #pragma unroll
    for (int i = 0; i < 8; i++) {
        int row = n0 + ty * 8 + i;
        float* cp = C + (size_t)row * 1024 + c0 + tx * 8;
        float4 r0 = make_float4(acc[i][0] + bias8[0], acc[i][1] + bias8[1],
                                acc[i][2] + bias8[2], acc[i][3] + bias8[3]);
        float4 r1 = make_float4(acc[i][4] + bias8[4], acc[i][5] + bias8[5],
                                acc[i][6] + bias8[6], acc[i][7] + bias8[7]);
        *(float4*)cp = r0;
        *(float4*)(cp + 4) = r1;
    }
}

// ---------------------------------------------------------------------------
// Hoisted h-recurrence scan. pre[nLocal][1024] chunk-local (bias included),
// col = dir*512 + gate*128 + k. 200 groups x 2 dirs = 400 WGs x 512 thr.
// Each group covers 2*SJ seqs; thread: k=tid&127, gp=(tid>>7)&1, hf=tid>>8,
// SJ seqs each. Weights wph4: hh-only float4 [2rows][2gates] pack.
// MODE 0: h -> outp[(gseq*T+te)*256 + dir*128 + k]; MODE 1: mean over t.
// ---------------------------------------------------------------------------
template <int MODE, int SJ>
__global__ __launch_bounds__(512) void word_scanH2(
    const float* __restrict__ pre,
    const float* __restrict__ wph4,  // [2][64][128][2][4]
    float* __restrict__ outp, int seqBase) {
    const int T = 40;
    const int HSTR = 3 * SJ;        // 12 or 6
    const int PSTR = 2 * SJ + 1;    // 9 or 5
    int wg = blockIdx.x;            // 400
    int dir = wg / 200;
    int grp = wg - dir * 200;
    int lbase = grp * (2 * SJ);
    int tid = threadIdx.x;
    int k = tid & 127;
    int gp = (tid >> 7) & 1;
    int hf = tid >> 8;
    int sb = hf * SJ;

    __shared__ float hs[128][HSTR];
    __shared__ float pa[2][128][PSTR];

    const float* wq = wph4 + ((size_t)dir * 64 * 128 + k) * 8 + gp * 4;

    float c[SJ], ms[SJ];
    #pragma unroll
    for (int j = 0; j < SJ; j++) { c[j] = 0.f; ms[j] = 0.f; }

    for (int t = 0; t < T; t++) {
        int te = dir ? (T - 1 - t) : t;
        float a0[SJ], a1[SJ];
        #pragma unroll
        for (int j = 0; j < SJ; j++) {
            size_t n = (size_t)(lbase + sb + j) * T + te;
            const float* pr = pre + n * 1024 + (size_t)dir * 512 + gp * 256 + k;
            a0[j] = pr[0];
            a1[j] = pr[128];
        }
        if (t > 0) {
            #pragma unroll 8
            for (int r2 = 0; r2 < 64; r2++) {
                float4 w = *(const float4*)(wq + (size_t)r2 * 1024);
                float xv0[SJ], xv1[SJ];
                if (SJ == 4) {
                    float4 t0 = *(const float4*)&hs[2 * r2][sb];
                    float4 t1 = *(const float4*)&hs[2 * r2 + 1][sb];
                    xv0[0] = t0.x; xv0[1] = t0.y; xv0[2] = t0.z; xv0[3] = t0.w;
                    xv1[0] = t1.x; xv1[1] = t1.y; xv1[2] = t1.z; xv1[3] = t1.w;
                } else {
                    float2 t0 = *(const float2*)&hs[2 * r2][sb];
                    float2 t1 = *(const float2*)&hs[2 * r2 + 1][sb];
                    xv0[0] = t0.x; xv0[1] = t0.y;
                    xv1[0] = t1.x; xv1[1] = t1.y;
                }
                #pragma unroll
                for (int j = 0; j < SJ; j++) {
                    a0[j] = fmaf(w.x, xv0[j], fmaf(w.z, xv1[j], a0[j]));
                    a1[j] = fmaf(w.y, xv0[j], fmaf(w.w, xv1[j], a1[j]));
                }
            }
        }
        if (gp == 1) {
            #pragma unroll
            for (int j = 0; j < SJ; j++) {
                pa[0][k][sb + j] = a0[j];
                pa[1][k][sb + j] = a1[j];
            }
        }
        __syncthreads();
        if (gp == 0) {
            float hv[SJ];
            #pragma unroll
            for (int j = 0; j < SJ; j++) {
                float iv = sigm(a0[j]);
                float fv = sigm(a1[j]);
                float gv = tanhf(pa[0][k][sb + j]);
                float ov = sigm(pa[1][k][sb + j]);
                c[j] = fv * c[j] + iv * gv;
                hv[j] = ov * tanhf(c[j]);
            }
            if (SJ == 4) {
                *(float4*)&hs[k][sb] = make_float4(hv[0], hv[1], hv[2], hv[3]);
            } else {
                *(float2*)&hs[k][sb] = make_float2(hv[0], hv[1]);
            }
            if (MODE == 0) {
                #pragma unroll
                for (int j = 0; j < SJ; j++) {
                    outp[(((size_t)(seqBase + lbase + sb + j)) * T + te) * 256 +
                         (size_t)dir * 128 + k] = hv[j];
                }
            } else {
                #pragma unroll
                for (int j = 0; j < SJ; j++) ms[j] += hv[j];
            }
        }
        __syncthreads();
    }
    if (MODE == 1 && gp == 0) {
        #pragma unroll
        for (int j = 0; j < SJ; j++) {
            outp[(size_t)(seqBase + lbase + sb + j) * 256 + (size_t)dir * 128 + k] =
                ms[j] * (1.f / T);
        }
    }
}

// ---------------------------------------------------------------------------
// Fused BiLSTM scan (fallback, no big ws): 8 seqs/WG, 400 WGs x 512 thr
// (2x occupancy of v2), float4 [2row][2gate] weights, 1 b128 LDS read/row.
// thread: k=tid&127, gp=(tid>>7)&1, hf=tid>>8, 4 seqs each.
// MODE 0: x = emb[ids] (K=E=128); MODE 1: x = xin rows (E=256), mean out.
// ---------------------------------------------------------------------------
template <int E, int MODE>
__global__ __launch_bounds__(512) void word_fused(
    const int* __restrict__ ids, const float* __restrict__ emb,
    const float* __restrict__ xin,
    const float* __restrict__ wpk4,  // [2][(E+128)/2][128][2][4]
    const float* __restrict__ bias,  // [2][512]
    float* __restrict__ outp) {
    const int T = 40;
    const int ROWS2 = (E + 128) / 2;
    int wg = blockIdx.x;             // 400
    int dir = wg / 200;
    int grp = wg - dir * 200;
    int base = grp * 8;
    int tid = threadIdx.x;
    int k = tid & 127;
    int gp = (tid >> 7) & 1;
    int hf = tid >> 8;
    int sb = hf * 4;

    __shared__ float xs[E][12];
    __shared__ float hs[128][12];
    __shared__ float pa[2][128][9];

    const float* wq = wpk4 + ((size_t)dir * ROWS2 * 128 + k) * 8 + gp * 4;
    const float* bb = bias + dir * 512;
    float bA = bb[gp * 256 + k];
    float bB = bb[gp * 256 + 128 + k];

    float c[4], ms[4];
    #pragma unroll
    for (int j = 0; j < 4; j++) { c[j] = 0.f; ms[j] = 0.f; }

    for (int t = 0; t < T; t++) {
        int te = dir ? (T - 1 - t) : t;
        // stage x rows for the 8 seqs into xs[e][s]
        {
            const int NF4 = 8 * (E / 4);
            for (int idx = tid; idx < NF4; idx += 512) {
                int s = idx / (E / 4);
                int e4 = idx - s * (E / 4);
                int seq = base + s;
                float4 v;
                if (MODE == 0) {
                    int id = ids[(size_t)seq * T + te];
                    v = *(const float4*)&emb[(size_t)id * 128 + e4 * 4];
                } else {
                    v = *(const float4*)&xin[((size_t)seq * T + te) * 256 + e4 * 4];
                }
                xs[e4 * 4 + 0][s] = v.x;
                xs[e4 * 4 + 1][s] = v.y;
                xs[e4 * 4 + 2][s] = v.z;
                xs[e4 * 4 + 3][s] = v.w;
            }
        }
        __syncthreads();

        float a0[4] = {bA, bA, bA, bA};
        float a1[4] = {bB, bB, bB, bB};

        // x-part: row pairs
        #pragma unroll 4
        for (int r2 = 0; r2 < E / 2; r2++) {
            float4 w = *(const float4*)(wq + (size_t)r2 * 1024);
            float4 t0 = *(const float4*)&xs[2 * r2][sb];
            float4 t1 = *(const float4*)&xs[2 * r2 + 1][sb];
            const float xv0[4] = {t0.x, t0.y, t0.z, t0.w};
            const float xv1[4] = {t1.x, t1.y, t1.z, t1.w};
            #pragma unroll
            for (int j = 0; j < 4; j++) {
                a0[j] = fmaf(w.x, xv0[j], fmaf(w.z, xv1[j], a0[j]));
                a1[j] = fmaf(w.y, xv0[j], fmaf(w.w, xv1[j], a1[j]));
            }
        }
        // h-part
        if (t > 0) {
            const float* wh = wq + (size_t)(E / 2) * 1024;
            #pragma unroll 4
            for (int r2 = 0; r2 < 64; r2++) {
                float4 w = *(const float4*)(wh + (size_t)r2 * 1024);
                float4 t0 = *(const float4*)&hs[2 * r2][sb];
                float4 t1 = *(const float4*)&hs[2 * r2 + 1][sb];
                const float xv0[4] = {t0.x, t0.y, t0.z, t0.w};
                const float xv1[4] = {t1.x, t1.y, t1.z, t1.w};
                #pragma unroll
                for (int j = 0; j < 4; j++) {
                    a0[j] = fmaf(w.x, xv0[j], fmaf(w.z, xv1[j], a0[j]));
                    a1[j] = fmaf(w.y, xv0[j], fmaf(w.w, xv1[j], a1[j]));
                }
            }
        }

        if (gp == 1) {
            #pragma unroll
            for (int j = 0; j < 4; j++) {
                pa[0][k][sb + j] = a0[j];  // g preact (bias incl.)
                pa[1][k][sb + j] = a1[j];  // o preact
            }
        }
        __syncthreads();
        if (gp == 0) {
            float hv[4];
            #pragma unroll
            for (int j = 0; j < 4; j++) {
                float iv = sigm(a0[j]);
                float fv = sigm(a1[j]);
                float gv = tanhf(pa[0][k][sb + j]);
                float ov = sigm(pa[1][k][sb + j]);
                c[j] = fv * c[j] + iv * gv;
                hv[j] = ov * tanhf(c[j]);
            }
            *(float4*)&hs[k][sb] = make_float4(hv[0], hv[1], hv[2], hv[3]);
            if (MODE == 0) {
                #pragma unroll
                for (int j = 0; j < 4; j++) {
                    outp[(((size_t)(base + sb + j)) * T + te) * 256 +
                         (size_t)dir * 128 + k] = hv[j];
                }
            } else {
                #pragma unroll
                for (int j = 0; j < 4; j++) ms[j] += hv[j];
            }
        }
        __syncthreads();
    }
    if (MODE == 1 && gp == 0) {
        #pragma unroll
        for (int j = 0; j < 4; j++) {
            outp[(size_t)(base + sb + j) * 256 + (size_t)dir * 128 + k] =
                ms[j] * (1.f / T);
        }
    }
}

// ---------------------------------------------------------------------------
// Small fp32 GEMM for doc layers: C[dir][n][g] = A[n][:256] @ Bt[dir][256][512]
// + bias. 64x64 tiles, 256 threads, 4x4 micro-tile.
// ---------------------------------------------------------------------------
__global__ __launch_bounds__(256) void gemm_pre(
    const float* __restrict__ A, const float* __restrict__ Bt,
    const float* __restrict__ bias, float* __restrict__ C) {
    int dir = blockIdx.z;
    const float* B = Bt + (size_t)dir * 256 * 512;
    float* Cp = C + (size_t)dir * 1600 * 512;
    const float* bb = bias + (size_t)dir * 512;
    int n0 = blockIdx.x * 64, g0 = blockIdx.y * 64;
    int tid = threadIdx.x;
    int tx = tid & 15, ty = tid >> 4;
    __shared__ float AsT[32][72];
    __shared__ float Bs[32][72];
    float acc[4][4];
    #pragma unroll
    for (int i = 0; i < 4; i++)
        #pragma unroll
        for (int j = 0; j < 4; j++) acc[i][j] = 0.f;

    for (int k0 = 0; k0 < 256; k0 += 32) {
        #pragma unroll
        for (int it = 0; it < 2; it++) {
            int idx = tid + it * 256;
            int n = idx & 63, e4 = idx >> 6;
            float4 v = *(const float4*)&A[(size_t)(n0 + n) * 256 + k0 + e4 * 4];
            AsT[e4 * 4 + 0][n] = v.x;
            AsT[e4 * 4 + 1][n] = v.y;
            AsT[e4 * 4 + 2][n] = v.z;
            AsT[e4 * 4 + 3][n] = v.w;
        }
        #pragma unroll
        for (int it = 0; it < 2; it++) {
            int idx = tid + it * 256;
            int g4 = idx & 15, e = idx >> 4;
            float4 v = *(const float4*)&B[(size_t)(k0 + e) * 512 + g0 + g4 * 4];
            *(float4*)&Bs[e][g4 * 4] = v;
        }
        __syncthreads();
        #pragma unroll 8
        for (int kk = 0; kk < 32; kk++) {
            float4 a = *(const float4*)&AsT[kk][ty * 4];
            float4 b = *(const float4*)&Bs[kk][tx * 4];
            const float av[4] = {a.x, a.y, a.z, a.w};
            const float bv[4] = {b.x, b.y, b.z, b.w};
            #pragma unroll
            for (int i = 0; i < 4; i++)
                #pragma unroll
                for (int j = 0; j < 4; j++)
                    acc[i][j] = fmaf(av[i], bv[j], acc[i][j]);
        }
        __syncthreads();
    }
    #pragma unroll
    for (int i = 0; i < 4; i++) {
        #pragma unroll
        for (int j = 0; j < 4; j++) {
            Cp[(size_t)(n0 + ty * 4 + i) * 512 + g0 + tx * 4 + j] =
                acc[i][j] + bb[g0 + tx * 4 + j];
        }
    }
}

// ---------------------------------------------------------------------------
// Doc-level BiLSTM scan: recurrent part only. One WG = (dir, 2 batch items).
// ---------------------------------------------------------------------------
__global__ __launch_bounds__(512) void doc_scan2(
    const float* __restrict__ pre,  // [2][32][50][512] (bias included)
    const float* __restrict__ whh,  // [2][128][512]
    float* __restrict__ outp) {     // [1600][256]
    const int S = 50;
    int wg = blockIdx.x;  // 32
    int dir = wg >> 4;
    int b0 = (wg & 15) * 2;
    int g = threadIdx.x;
    int k = g & 127, su = g >> 7;
    __shared__ float hsd[2][128];
    __shared__ float paD[2][512];
    const float* W = whh + (size_t)dir * 128 * 512;
    const float* p0 = pre + ((size_t)dir * 1600 + (size_t)b0 * 50) * 512;
    float cst = 0.f;
    for (int t = 0; t < S; t++) {
        int te = dir ? (S - 1 - t) : t;
        float a0 = p0[(size_t)te * 512 + g];
        float a1 = p0[((size_t)(50 + te)) * 512 + g];
        if (t > 0) {
            #pragma unroll 8
            for (int r = 0; r < 128; r++) {
                float w = W[(size_t)r * 512 + g];
                a0 = fmaf(w, hsd[0][r], a0);
                a1 = fmaf(w, hsd[1][r], a1);
            }
        }
        paD[0][g] = a0;
        paD[1][g] = a1;
        __syncthreads();
        if (g < 256) {
            float pi = paD[su][k], pf = paD[su][128 + k];
            float pg = paD[su][256 + k], po = paD[su][384 + k];
            float iv = sigm(pi), fv = sigm(pf), gv = tanhf(pg), ov = sigm(po);
            cst = fv * cst + iv * gv;
            float hv = ov * tanhf(cst);
            hsd[su][k] = hv;
            outp[((size_t)(b0 + su) * 50 + te) * 256 + (size_t)dir * 128 + k] = hv;
        }
        __syncthreads();
    }
}

// ---------------------------------------------------------------------------
// Head kernel (unchanged).
// ---------------------------------------------------------------------------
__global__ __launch_bounds__(256) void head_kernel(
    const float* __restrict__ outv, const float* __restrict__ content_w,
    const float* __restrict__ content_b, const float* __restrict__ doclT,
    const float* __restrict__ docl_b, const float* __restrict__ salT,
    const float* __restrict__ sal_b, const float* __restrict__ novT,
    const float* __restrict__ nov_b, float* __restrict__ outp) {
    const int S = 50, D = 256;
    int b = blockIdx.x;
    int tid = threadIdx.x;
    __shared__ float oL[50][257];
    __shared__ float mb[256];
    __shared__ float de[256];
    __shared__ float svec[256];
    __shared__ float nvec[256];
    __shared__ float tsum[256];
    __shared__ float predL[64];
    __shared__ float nvL[64];
    __shared__ float red[4][64];

    const float* ob = outv + (size_t)b * S * D;
    for (int i = tid; i < S * D; i += 256) {
        int s = i >> 8, d = i & 255;
        oL[s][d] = ob[i];
    }
    __syncthreads();
    {
        float m = 0;
        for (int s = 0; s < S; s++) m += oL[s][tid];
        mb[tid] = m * (1.f / S);
    }
    __syncthreads();
    {
        float acc = docl_b[tid];
        for (int d = 0; d < D; d++) acc = fmaf(doclT[d * 256 + tid], mb[d], acc);
        de[tid] = tanhf(acc);
    }
    __syncthreads();
    {
        float acc = sal_b[tid];
        for (int d = 0; d < D; d++) acc = fmaf(salT[d * 256 + tid], de[d], acc);
        svec[tid] = acc;
    }
    __syncthreads();
    {
        int s = tid & 63, pw = tid >> 6;
        float ca = 0, sa = 0;
        if (s < S) {
            for (int i = 0; i < 64; i++) {
                int d = pw * 64 + i;
                float ov = oL[s][d];
                ca = fmaf(ov, content_w[d], ca);
                sa = fmaf(ov, svec[d], sa);
            }
        }
        red[pw][s] = ca + sa;
    }
    __syncthreads();
    if (tid < S) {
        predL[tid] = content_b[0] + red[0][tid] + red[1][tid] + red[2][tid] + red[3][tid];
    }
    float summ = 0.f;
    __syncthreads();
    for (int it = 0; it < S; ++it) {
        tsum[tid] = tanhf(summ);
        __syncthreads();
        {
            float acc = nov_b[tid];
            for (int d = 0; d < D; d++) acc = fmaf(novT[d * 256 + tid], tsum[d], acc);
            nvec[tid] = acc;
        }
        __syncthreads();
        {
            int s = tid & 63, pw = tid >> 6;
            float na = 0;
            if (s < S) {
                for (int i = 0; i < 64; i++) {
                    int d = pw * 64 + i;
                    na = fmaf(oL[s][d], nvec[d], na);
                }
            }
            red[pw][s] = na;
        }
        __syncthreads();
        if (tid < S) nvL[tid] = red[0][tid] + red[1][tid] + red[2][tid] + red[3][tid];
        __syncthreads();
        float prob = sigm(predL[it] - nvL[it]);
        summ = fmaf(prob, oL[it][tid], summ);
        __syncthreads();
    }
    if (tid < S) outp[(size_t)b * S + tid] = predL[tid] - nvL[tid];
}

// ---------------------------------------------------------------------------
extern "C" void kernel_launch(void* const* d_in, const int* in_sizes, int n_in,
                              void* d_out, int out_size, void* d_ws, size_t ws_size,
                              hipStream_t stream) {
    const int* ids = (const int*)d_in[0];
    const float* emb = (const float*)d_in[1];
    const float* e_ih0 = (const float*)d_in[2];
    const float* e_hh0 = (const float*)d_in[3];
    const float* e_b0 = (const float*)d_in[4];
    const float* e_ih1 = (const float*)d_in[5];
    const float* e_hh1 = (const float*)d_in[6];
    const float* e_b1 = (const float*)d_in[7];
    const float* d_ih0 = (const float*)d_in[8];
    const float* d_hh0 = (const float*)d_in[9];
    const float* d_b0 = (const float*)d_in[10];
    const float* d_ih1 = (const float*)d_in[11];
    const float* d_hh1 = (const float*)d_in[12];
    const float* d_b1 = (const float*)d_in[13];
    const float* content_w = (const float*)d_in[14];
    const float* content_b = (const float*)d_in[15];
    const float* docl_w = (const float*)d_in[16];
    const float* docl_b = (const float*)d_in[17];
    const float* sal_w = (const float*)d_in[18];
    const float* sal_b = (const float*)d_in[19];
    const float* nov_w = (const float*)d_in[20];
    const float* nov_b = (const float*)d_in[21];
    float* outp = (float*)d_out;

    float* ws = (float*)d_ws;
    size_t off = 0;
    auto alloc = [&](size_t n) { float* p = ws + off; off += n; return p; };
    // --- fused-path packed weights ---
    float* wpk4_0 = alloc((size_t)2 * 256 * 512);
    float* wpk4_1 = alloc((size_t)2 * 384 * 512);
    // --- hoisted-path weights ---
    float* wph4_0 = alloc((size_t)2 * 128 * 512);
    float* wph4_1 = alloc((size_t)2 * 128 * 512);
    float* btw0 = alloc((size_t)128 * 1024);
    float* btw1 = alloc((size_t)256 * 1024);
    float* bv0 = alloc(1024);
    float* bv1 = alloc(1024);
    // --- doc / head weights ---
    float* bT_d0 = alloc((size_t)2 * 256 * 512);
    float* whh_d0 = alloc((size_t)2 * 128 * 512);
    float* bT_d1 = alloc((size_t)2 * 256 * 512);
    float* whh_d1 = alloc((size_t)2 * 128 * 512);
    float* wT_docl = alloc((size_t)256 * 256);
    float* wT_sal = alloc((size_t)256 * 256);
    float* wT_nov = alloc((size_t)256 * 256);
    // --- activations ---
    float* sent = alloc((size_t)1600 * 256);
    float* pre_d0 = alloc((size_t)2 * 1600 * 512);
    float* d0out = alloc((size_t)1600 * 256);
    float* pre_d1 = alloc((size_t)2 * 1600 * 512);
    float* dout = alloc((size_t)1600 * 256);
    float* h0out = alloc((size_t)64000 * 256);
    size_t base = off;
    size_t needA = (base + (size_t)64000 * 1024) * 4;  // full pre (262 MB)
    size_t needB = (base + (size_t)32000 * 1024) * 4;  // half pre (131 MB)
    float* pre = ws + base;  // chunk-sized, tail of workspace
    (void)in_sizes; (void)n_in; (void)out_size;

    int tier = (ws_size >= needA) ? 2 : (ws_size >= needB) ? 1 : 0;

    dim3 tb(32, 8);
    // --- doc/head weight prep (all paths) ---
    transpose_k<<<dim3(256 / 32, 512 / 32, 2), tb, 0, stream>>>(d_ih0, bT_d0, 512, 256);
    transpose_k<<<dim3(128 / 32, 512 / 32, 2), tb, 0, stream>>>(d_hh0, whh_d0, 512, 128);
    transpose_k<<<dim3(256 / 32, 512 / 32, 2), tb, 0, stream>>>(d_ih1, bT_d1, 512, 256);
    transpose_k<<<dim3(128 / 32, 512 / 32, 2), tb, 0, stream>>>(d_hh1, whh_d1, 512, 128);
    transpose_k<<<dim3(256 / 32, 256 / 32, 1), tb, 0, stream>>>(docl_w, wT_docl, 256, 256);
    transpose_k<<<dim3(256 / 32, 256 / 32, 1), tb, 0, stream>>>(sal_w, wT_sal, 256, 256);
    transpose_k<<<dim3(256 / 32, 256 / 32, 1), tb, 0, stream>>>(nov_w, wT_nov, 256, 256);

    if (tier > 0) {
        // hoisted: hh-only packs + W_ih^T, then per-chunk GEMM + h-scan
        pack_w4<<<256, 256, 0, stream>>>(e_hh0, e_hh0, wph4_0, 0);
        pack_w4<<<256, 256, 0, stream>>>(e_hh1, e_hh1, wph4_1, 0);
        pack_bt<<<256, 256, 0, stream>>>(e_ih0, e_b0, btw0, bv0, 128);
        pack_bt<<<512, 256, 0, stream>>>(e_ih1, e_b1, btw1, bv1, 256);

        int CS = (tier == 2) ? 1600 : 800;   // seqs per chunk
        int nch = 1600 / CS;
        for (int c = 0; c < nch; ++c) {
            gemm_x<128, 1><<<dim3(CS * 40 / 128, 8), 256, 0, stream>>>(
                nullptr, ids + (size_t)c * CS * 40, emb, btw0, bv0, pre);
            if (tier == 2)
                word_scanH2<0, 4><<<400, 512, 0, stream>>>(pre, wph4_0, h0out, c * CS);
            else
                word_scanH2<0, 2><<<400, 512, 0, stream>>>(pre, wph4_0, h0out, c * CS);
        }
        for (int c = 0; c < nch; ++c) {
            gemm_x<256, 0><<<dim3(CS * 40 / 128, 8), 256, 0, stream>>>(
                h0out + (size_t)c * CS * 40 * 256, nullptr, nullptr, btw1, bv1, pre);
            if (tier == 2)
                word_scanH2<1, 4><<<400, 512, 0, stream>>>(pre, wph4_1, sent, c * CS);
            else
                word_scanH2<1, 2><<<400, 512, 0, stream>>>(pre, wph4_1, sent, c * CS);
        }
    } else {
        // fused fallback: 8 seqs/WG, 400 WGs, float4 weight pack
        pack_w4<<<512, 256, 0, stream>>>(e_ih0, e_hh0, wpk4_0, 128);
        pack_w4<<<768, 256, 0, stream>>>(e_ih1, e_hh1, wpk4_1, 256);
        word_fused<128, 0><<<400, 512, 0, stream>>>(ids, emb, nullptr, wpk4_0,
                                                    e_b0, h0out);
        word_fused<256, 1><<<400, 512, 0, stream>>>(nullptr, nullptr, h0out, wpk4_1,
                                                    e_b1, sent);
    }

    // doc-level BiLSTM layers
    gemm_pre<<<dim3(25, 8, 2), 256, 0, stream>>>(sent, bT_d0, d_b0, pre_d0);
    doc_scan2<<<32, 512, 0, stream>>>(pre_d0, whh_d0, d0out);
    gemm_pre<<<dim3(25, 8, 2), 256, 0, stream>>>(d0out, bT_d1, d_b1, pre_d1);
    doc_scan2<<<32, 512, 0, stream>>>(pre_d1, whh_d1, dout);

    // head
    head_kernel<<<32, 256, 0, stream>>>(dout, content_w, content_b, wT_docl, docl_b,
                                        wT_sal, sal_b, wT_nov, nov_b, outp);
}